// Round 4
// baseline (564.625 us; speedup 1.0000x reference)
//
#include <hip/hip_runtime.h>

#define N_E 512
#define DIM 64
#define HW  4096                 // 64*64
#define NPTS (32 * HW)           // 131072 points
#define OUT_ELEMS (NPTS * DIM)   // 8388608
#define PTS_PER_BLOCK 128        // 2 threads per point

typedef float v2f __attribute__((ext_vector_type(2)));

__global__ void vq_zero_loss(float* __restrict__ out) {
    out[0] = 0.0f;
}

__global__ __launch_bounds__(256) void vq_main(
    const float* __restrict__ z,    // [32, 64, 64, 64] NCHW
    const float* __restrict__ emb,  // [512, 64]
    float* __restrict__ out)        // [0] = loss, [1..] = z_q_st NCHW
{
    const int t    = threadIdx.x;
    const int half = t >> 7;                      // 0: entries 0-255, 1: 256-511
    const int pl   = t & 127;                     // local point
    const int p    = blockIdx.x * PTS_PER_BLOCK + pl;
    const int b    = p >> 12;
    const int hw   = p & 4095;

    __shared__ float se2[N_E];
    __shared__ float sdm[256];
    __shared__ int   sim[256];
    __shared__ float sred[4];

    // ---- per-block e2 = ||emb_row||^2 (each thread: 2 rows) ----
    {
        const float* r0 = emb + (2 * t) * DIM;
        float s0 = 0.0f, s1 = 0.0f;
#pragma unroll
        for (int k = 0; k < DIM; ++k) {
            float v0 = r0[k];       s0 = fmaf(v0, v0, s0);
            float v1 = r0[DIM + k]; s1 = fmaf(v1, v1, s1);
        }
        se2[2 * t]     = s0;
        se2[2 * t + 1] = s1;
    }

    // ---- load full z row into VGPR pairs (coalesced per channel) ----
    const float* zb = z + (size_t)(b * DIM) * HW + hw;
    v2f zv[32];
    float z2 = 0.0f;
#pragma unroll
    for (int k = 0; k < 32; ++k) {
        float lo = zb[(size_t)(2 * k)     * HW];
        float hi = zb[(size_t)(2 * k + 1) * HW];
        zv[k][0] = lo; zv[k][1] = hi;
        z2 = fmaf(lo, lo, z2);
        z2 = fmaf(hi, hi, z2);
    }
    __syncthreads();

    // ---- scan this half's 256 codebook rows with packed fp32 FMA ----
    float dmin = 3.4e38f;
    int   imin = 0;
    const int ebase = half << 8;
#pragma unroll 1
    for (int e = 0; e < 256; e += 2) {
        const v2f* er0 = (const v2f*)(emb + (ebase + e) * DIM);
        const v2f* er1 = er0 + 32;
        v2f a0 = {0.f, 0.f}, a1 = {0.f, 0.f}, c0 = {0.f, 0.f}, c1 = {0.f, 0.f};
#pragma unroll
        for (int k = 0; k < 32; k += 2) {
            v2f e00 = er0[k], e01 = er0[k + 1];
            v2f e10 = er1[k], e11 = er1[k + 1];
            asm("v_pk_fma_f32 %0, %1, %2, %0" : "+v"(a0) : "v"(zv[k]),     "s"(e00));
            asm("v_pk_fma_f32 %0, %1, %2, %0" : "+v"(a1) : "v"(zv[k + 1]), "s"(e01));
            asm("v_pk_fma_f32 %0, %1, %2, %0" : "+v"(c0) : "v"(zv[k]),     "s"(e10));
            asm("v_pk_fma_f32 %0, %1, %2, %0" : "+v"(c1) : "v"(zv[k + 1]), "s"(e11));
        }
        float dot0 = (a0[0] + a0[1]) + (a1[0] + a1[1]);
        float dot1 = (c0[0] + c0[1]) + (c1[0] + c1[1]);
        float d0 = fmaf(-2.0f, dot0, z2 + se2[ebase + e]);
        float d1 = fmaf(-2.0f, dot1, z2 + se2[ebase + e + 1]);
        if (d0 < dmin) { dmin = d0; imin = ebase + e; }
        if (d1 < dmin) { dmin = d1; imin = ebase + e + 1; }
    }

    // ---- combine halves (first-index tie-break: half0 wins ties) ----
    sdm[t] = dmin;
    sim[t] = imin;
    __syncthreads();
    const int ot = t ^ 128;
    float od = sdm[ot];
    int   oi = sim[ot];
    float dA = (half == 0) ? dmin : od;   int iA = (half == 0) ? imin : oi;
    float dB = (half == 0) ? od   : dmin; int iB = (half == 0) ? oi   : imin;
    const int w = (dB < dA) ? iB : iA;

    // ---- epilogue: each half writes 32 channels + partial loss ----
    float acc = 0.0f;
    if (half == 0) {
        const float* qrow = emb + w * DIM;
        float* op = out + 1 + (size_t)(b * DIM) * HW + hw;
#pragma unroll
        for (int c = 0; c < 32; ++c) {
            float v = qrow[c];
            op[(size_t)c * HW] = v;
            float zc = (c & 1) ? zv[c >> 1][1] : zv[c >> 1][0];
            float d = v - zc;
            acc = fmaf(d, d, acc);
        }
    } else {
        const float* qrow = emb + w * DIM + 32;
        float* op = out + 1 + (size_t)(b * DIM + 32) * HW + hw;
#pragma unroll
        for (int c = 0; c < 32; ++c) {
            float v = qrow[c];
            op[(size_t)c * HW] = v;
            float zc = (c & 1) ? zv[16 + (c >> 1)][1] : zv[16 + (c >> 1)][0];
            float d = v - zc;
            acc = fmaf(d, d, acc);
        }
    }

    // ---- block loss reduction, one atomic per block ----
#pragma unroll
    for (int o = 32; o > 0; o >>= 1) acc += __shfl_down(acc, o, 64);
    if ((t & 63) == 0) sred[t >> 6] = acc;
    __syncthreads();
    if (t == 0) {
        float s = (sred[0] + sred[1]) + (sred[2] + sred[3]);
        atomicAdd(out, s * (1.25f / (float)OUT_ELEMS));
    }
}

extern "C" void kernel_launch(void* const* d_in, const int* in_sizes, int n_in,
                              void* d_out, int out_size, void* d_ws, size_t ws_size,
                              hipStream_t stream) {
    const float* z   = (const float*)d_in[0];
    const float* emb = (const float*)d_in[1];
    float* out = (float*)d_out;

    vq_zero_loss<<<1, 1, 0, stream>>>(out);
    vq_main<<<NPTS / PTS_PER_BLOCK, 256, 0, stream>>>(z, emb, out);
}

// Round 5
// 404.444 us; speedup vs baseline: 1.3961x; 1.3961x over previous
//
#include <hip/hip_runtime.h>

#define N_E 512
#define DIM 64
#define HW  4096                 // 64*64
#define NPTS (32 * HW)           // 131072 points
#define OUT_ELEMS (NPTS * DIM)   // 8388608

typedef float v2f __attribute__((ext_vector_type(2)));

__global__ void vq_zero_loss(float* __restrict__ out) {
    out[0] = 0.0f;
}

// 256 threads = 4 waves. Each block: 128 points. Wave q scans codebook
// rows [q*128, q*128+128) for all 128 points; each thread owns 2 points
// (z fully in VGPRs). emb rows are wave-uniform -> L1 broadcast; pointer
// is laundered through v0 so the compiler can't scalarize to s_load
// (round-2/4 lesson: "s"-operand emb serialized on lgkmcnt, 529us).
__global__ __launch_bounds__(256, 3) void vq_main(
    const float* __restrict__ z,    // [32, 64, 64, 64] NCHW
    const float* __restrict__ emb,  // [512, 64]
    float* __restrict__ out)        // [0] = loss, [1..] = z_q_st NCHW
{
    const int t = threadIdx.x;
    const int q = t >> 6;           // wave id = codebook quarter
    const int l = t & 63;

    __shared__ float se2[N_E];
    __shared__ float sdm[4][128];
    __shared__ int   sim[4][128];
    __shared__ int   swin[128];
    __shared__ float sred[4];

    // laundered zero: compiler must assume divergent -> keeps vector loads
    uint32_t zzero;
    asm volatile("v_mov_b32 %0, 0" : "=v"(zzero));

    // ---- e2 table: each thread does 2 rows (per-thread addresses) ----
    {
        const float* r0 = emb + (2 * t) * DIM;
        float s0 = 0.f, s1 = 0.f;
#pragma unroll
        for (int k = 0; k < DIM; ++k) {
            float a = r0[k];       s0 = fmaf(a, a, s0);
            float c = r0[DIM + k]; s1 = fmaf(c, c, s1);
        }
        se2[2 * t]     = s0;
        se2[2 * t + 1] = s1;
    }

    // ---- load z for this thread's 2 points (coalesced per channel) ----
    const int p0  = blockIdx.x * 128;      // 128 points/block, same image b
    const int b   = p0 >> 12;
    const int hwA = (p0 & 4095) + l;
    const int hwB = hwA + 64;
    const float* zb = z + (size_t)b * DIM * HW;

    v2f zA[32], zB[32];
    float z2A = 0.f, z2B = 0.f;
#pragma unroll
    for (int k = 0; k < 32; ++k) {
        float a0 = zb[(size_t)(2 * k)     * HW + hwA];
        float a1 = zb[(size_t)(2 * k + 1) * HW + hwA];
        float b0 = zb[(size_t)(2 * k)     * HW + hwB];
        float b1 = zb[(size_t)(2 * k + 1) * HW + hwB];
        zA[k][0] = a0; zA[k][1] = a1;
        zB[k][0] = b0; zB[k][1] = b1;
        z2A = fmaf(a0, a0, z2A); z2A = fmaf(a1, a1, z2A);
        z2B = fmaf(b0, b0, z2B); z2B = fmaf(b1, b1, z2B);
    }
    __syncthreads();

    // ---- scan this wave's 128 codebook rows with packed fp32 FMA ----
    const float4* ebase = (const float4*)emb + zzero;   // laundered
    float dminA = 3.4e38f, dminB = 3.4e38f;
    int   iminA = 0,       iminB = 0;
#pragma unroll 1
    for (int r = q * 128; r < q * 128 + 128; ++r) {
        const float4* er = ebase + r * 16;
        v2f aA0 = {0.f,0.f}, aA1 = {0.f,0.f}, aB0 = {0.f,0.f}, aB1 = {0.f,0.f};
#pragma unroll
        for (int h = 0; h < 4; ++h) {
            float4 q0 = er[h * 4 + 0], q1 = er[h * 4 + 1];
            float4 q2 = er[h * 4 + 2], q3 = er[h * 4 + 3];
            v2f e0 = {q0.x, q0.y}, e1 = {q0.z, q0.w};
            v2f e2 = {q1.x, q1.y}, e3 = {q1.z, q1.w};
            v2f e4 = {q2.x, q2.y}, e5 = {q2.z, q2.w};
            v2f e6 = {q3.x, q3.y}, e7 = {q3.z, q3.w};
            const int kb = h * 8;
            asm("v_pk_fma_f32 %0, %1, %2, %0" : "+v"(aA0) : "v"(zA[kb + 0]), "v"(e0));
            asm("v_pk_fma_f32 %0, %1, %2, %0" : "+v"(aB0) : "v"(zB[kb + 0]), "v"(e0));
            asm("v_pk_fma_f32 %0, %1, %2, %0" : "+v"(aA1) : "v"(zA[kb + 1]), "v"(e1));
            asm("v_pk_fma_f32 %0, %1, %2, %0" : "+v"(aB1) : "v"(zB[kb + 1]), "v"(e1));
            asm("v_pk_fma_f32 %0, %1, %2, %0" : "+v"(aA0) : "v"(zA[kb + 2]), "v"(e2));
            asm("v_pk_fma_f32 %0, %1, %2, %0" : "+v"(aB0) : "v"(zB[kb + 2]), "v"(e2));
            asm("v_pk_fma_f32 %0, %1, %2, %0" : "+v"(aA1) : "v"(zA[kb + 3]), "v"(e3));
            asm("v_pk_fma_f32 %0, %1, %2, %0" : "+v"(aB1) : "v"(zB[kb + 3]), "v"(e3));
            asm("v_pk_fma_f32 %0, %1, %2, %0" : "+v"(aA0) : "v"(zA[kb + 4]), "v"(e4));
            asm("v_pk_fma_f32 %0, %1, %2, %0" : "+v"(aB0) : "v"(zB[kb + 4]), "v"(e4));
            asm("v_pk_fma_f32 %0, %1, %2, %0" : "+v"(aA1) : "v"(zA[kb + 5]), "v"(e5));
            asm("v_pk_fma_f32 %0, %1, %2, %0" : "+v"(aB1) : "v"(zB[kb + 5]), "v"(e5));
            asm("v_pk_fma_f32 %0, %1, %2, %0" : "+v"(aA0) : "v"(zA[kb + 6]), "v"(e6));
            asm("v_pk_fma_f32 %0, %1, %2, %0" : "+v"(aB0) : "v"(zB[kb + 6]), "v"(e6));
            asm("v_pk_fma_f32 %0, %1, %2, %0" : "+v"(aA1) : "v"(zA[kb + 7]), "v"(e7));
            asm("v_pk_fma_f32 %0, %1, %2, %0" : "+v"(aB1) : "v"(zB[kb + 7]), "v"(e7));
        }
        float dotA = (aA0[0] + aA0[1]) + (aA1[0] + aA1[1]);
        float dotB = (aB0[0] + aB0[1]) + (aB1[0] + aB1[1]);
        float e2r  = se2[r];
        float dA = fmaf(-2.0f, dotA, z2A + e2r);
        float dB = fmaf(-2.0f, dotB, z2B + e2r);
        if (dA < dminA) { dminA = dA; iminA = r; }
        if (dB < dminB) { dminB = dB; iminB = r; }
    }

    // ---- combine the 4 quarters (ascending q + strict < = first-index) ----
    sdm[q][l]      = dminA;  sim[q][l]      = iminA;
    sdm[q][64 + l] = dminB;  sim[q][64 + l] = iminB;
    __syncthreads();
    if (t < 128) {
        float bd = sdm[0][t]; int bi = sim[0][t];
#pragma unroll
        for (int qq = 1; qq < 4; ++qq) {
            float d2 = sdm[qq][t];
            int   i2 = sim[qq][t];
            if (d2 < bd) { bd = d2; bi = i2; }
        }
        swin[t] = bi;
    }
    __syncthreads();

    // ---- epilogue: wave q writes channels [q*16, q*16+16) of its 2 points ----
    const int wA = swin[l], wB = swin[64 + l];
    float* ob = out + 1 + (size_t)b * DIM * HW;
    float acc = 0.f;

#define EPI(Q)                                                          \
    {                                                                   \
        _Pragma("unroll")                                               \
        for (int j = 0; j < 16; ++j) {                                  \
            const int c = (Q) * 16 + j;                                 \
            float vA = emb[wA * DIM + c];                               \
            float vB = emb[wB * DIM + c];                               \
            ob[(size_t)c * HW + hwA] = vA;                              \
            ob[(size_t)c * HW + hwB] = vB;                              \
            float zAc = (c & 1) ? zA[c >> 1][1] : zA[c >> 1][0];        \
            float zBc = (c & 1) ? zB[c >> 1][1] : zB[c >> 1][0];        \
            float dA_ = vA - zAc, dB_ = vB - zBc;                       \
            acc = fmaf(dA_, dA_, acc);                                  \
            acc = fmaf(dB_, dB_, acc);                                  \
        }                                                               \
    }
    if (q == 0)      EPI(0)
    else if (q == 1) EPI(1)
    else if (q == 2) EPI(2)
    else             EPI(3)
#undef EPI

    // ---- loss reduction: wave shuffle -> LDS -> one atomic per block ----
#pragma unroll
    for (int o = 32; o > 0; o >>= 1) acc += __shfl_down(acc, o, 64);
    if (l == 0) sred[q] = acc;
    __syncthreads();
    if (t == 0) {
        float s = (sred[0] + sred[1]) + (sred[2] + sred[3]);
        atomicAdd(out, s * (1.25f / (float)OUT_ELEMS));
    }
}

extern "C" void kernel_launch(void* const* d_in, const int* in_sizes, int n_in,
                              void* d_out, int out_size, void* d_ws, size_t ws_size,
                              hipStream_t stream) {
    const float* z   = (const float*)d_in[0];
    const float* emb = (const float*)d_in[1];
    float* out = (float*)d_out;

    vq_zero_loss<<<1, 1, 0, stream>>>(out);
    vq_main<<<NPTS / 128, 256, 0, stream>>>(z, emb, out);
}

// Round 6
// 208.240 us; speedup vs baseline: 2.7114x; 1.9422x over previous
//
#include <hip/hip_runtime.h>

#define N_E 512
#define DIM 64
#define HW  4096                 // 64*64
#define NPTS (32 * HW)           // 131072 points
#define OUT_ELEMS (NPTS * DIM)   // 8388608

typedef float v2f __attribute__((ext_vector_type(2)));

__global__ void vq_zero_loss(float* __restrict__ out) {
    out[0] = 0.0f;
}

// 256 threads = 4 waves, 128 points/block, 1024 blocks.
// 1 point per thread (z row in 32 v2f = 64 VGPR; round-5 lesson: 2 points
// spilled to scratch -> 57MB of extra HBM writes). Codebook split in halves:
// waves 0,1 scan rows 0-255, waves 2,3 scan rows 256-511.
// half is readfirstlane'd so emb addressing is provably wave-uniform ->
// compiler scalarizes emb loads to s_load (round-4 lesson: "s" asm
// constraints on vector-loaded data forced readfirstlane chains, 529us).
// Packed fp32 FMA via __builtin_elementwise_fma on float2.
__global__ __launch_bounds__(256) void vq_main(
    const float* __restrict__ z,    // [32, 64, 64, 64] NCHW
    const float* __restrict__ emb,  // [512, 64]
    float* __restrict__ out)        // [0] = loss, [1..] = z_q_st NCHW
{
    const int t    = threadIdx.x;
    const int half = __builtin_amdgcn_readfirstlane(t >> 7);  // SGPR, uniform
    const int pl   = t & 127;

    __shared__ float se2[N_E];
    __shared__ float sdm[256];
    __shared__ int   sim[256];
    __shared__ float sred[4];

    // ---- e2 table: each thread does 2 rows ----
    {
        const float* r0 = emb + (2 * t) * DIM;
        float s0 = 0.f, s1 = 0.f;
#pragma unroll
        for (int k = 0; k < DIM; ++k) {
            float a = r0[k];       s0 = fmaf(a, a, s0);
            float c = r0[DIM + k]; s1 = fmaf(c, c, s1);
        }
        se2[2 * t]     = s0;
        se2[2 * t + 1] = s1;
    }

    // ---- load this point's z row (coalesced per channel) ----
    const int p0 = blockIdx.x * 128;
    const int b  = p0 >> 12;
    const int hw = (p0 & 4095) + pl;
    const float* zb = z + (size_t)b * DIM * HW + hw;

    v2f zv[32];
    float z2 = 0.f;
#pragma unroll
    for (int k = 0; k < 32; ++k) {
        float lo = zb[(size_t)(2 * k)     * HW];
        float hi = zb[(size_t)(2 * k + 1) * HW];
        zv[k][0] = lo; zv[k][1] = hi;
        z2 = fmaf(lo, lo, z2);
        z2 = fmaf(hi, hi, z2);
    }
    __syncthreads();

    // ---- scan this half's 256 rows; emb loads wave-uniform (scalar pipe) ----
    const float*  eb  = emb + half * (256 * DIM);
    const float*  e2b = se2 + half * 256;
    float dmin = 3.4e38f;
    int   imin = 0;
#pragma unroll 2
    for (int e = 0; e < 256; ++e) {
        const float4* er4 = (const float4*)(eb + e * DIM);   // 16 x float4
        v2f a[8];
#pragma unroll
        for (int c = 0; c < 8; ++c) a[c] = (v2f){0.f, 0.f};
#pragma unroll
        for (int j = 0; j < 16; ++j) {
            float4 f = er4[j];
            v2f e0 = {f.x, f.y};
            v2f e1 = {f.z, f.w};
            a[(2 * j)     & 7] = __builtin_elementwise_fma(zv[2 * j],     e0, a[(2 * j)     & 7]);
            a[(2 * j + 1) & 7] = __builtin_elementwise_fma(zv[2 * j + 1], e1, a[(2 * j + 1) & 7]);
        }
        v2f s01 = a[0] + a[1], s23 = a[2] + a[3];
        v2f s45 = a[4] + a[5], s67 = a[6] + a[7];
        v2f s = (s01 + s23) + (s45 + s67);
        float dot = s[0] + s[1];
        float d = fmaf(-2.0f, dot, z2 + e2b[e]);
        if (d < dmin) { dmin = d; imin = e; }
    }
    imin += half * 256;   // strict-< ascending scan => first-index preserved

    // ---- combine halves (half0 wins ties => global first-index) ----
    sdm[t] = dmin;
    sim[t] = imin;
    __syncthreads();
    const int ot = t ^ 128;
    float od = sdm[ot];
    int   oi = sim[ot];
    float dA = (half == 0) ? dmin : od;   int iA = (half == 0) ? imin : oi;
    float dB = (half == 0) ? od   : dmin; int iB = (half == 0) ? oi   : imin;
    const int w = (dB < dA) ? iB : iA;

    // ---- epilogue: half0 writes ch 0-31, half1 ch 32-63 of its point ----
    float acc = 0.f;
    float* ob = out + 1 + (size_t)b * DIM * HW + hw;
    if (half == 0) {
        const float* qrow = emb + w * DIM;
#pragma unroll
        for (int c = 0; c < 32; ++c) {
            float v = qrow[c];
            ob[(size_t)c * HW] = v;
            float zc = (c & 1) ? zv[c >> 1][1] : zv[c >> 1][0];
            float d = v - zc;
            acc = fmaf(d, d, acc);
        }
    } else {
        const float* qrow = emb + w * DIM + 32;
#pragma unroll
        for (int c = 0; c < 32; ++c) {
            float v = qrow[c];
            ob[(size_t)(32 + c) * HW] = v;
            float zc = (c & 1) ? zv[16 + (c >> 1)][1] : zv[16 + (c >> 1)][0];
            float d = v - zc;
            acc = fmaf(d, d, acc);
        }
    }

    // ---- loss reduction: wave shuffle -> LDS -> one atomic per block ----
#pragma unroll
    for (int o = 32; o > 0; o >>= 1) acc += __shfl_down(acc, o, 64);
    if ((t & 63) == 0) sred[t >> 6] = acc;
    __syncthreads();
    if (t == 0) {
        float s = (sred[0] + sred[1]) + (sred[2] + sred[3]);
        atomicAdd(out, s * (1.25f / (float)OUT_ELEMS));
    }
}

extern "C" void kernel_launch(void* const* d_in, const int* in_sizes, int n_in,
                              void* d_out, int out_size, void* d_ws, size_t ws_size,
                              hipStream_t stream) {
    const float* z   = (const float*)d_in[0];
    const float* emb = (const float*)d_in[1];
    float* out = (float*)d_out;

    vq_zero_loss<<<1, 1, 0, stream>>>(out);
    vq_main<<<NPTS / 128, 256, 0, stream>>>(z, emb, out);
}

// Round 9
// 205.328 us; speedup vs baseline: 2.7499x; 1.0142x over previous
//
#include <hip/hip_runtime.h>

#define N_E 512
#define DIM 64
#define HW  4096                 // 64*64
#define NPTS (32 * HW)           // 131072 points
#define OUT_ELEMS (NPTS * DIM)   // 8388608

typedef float v2f __attribute__((ext_vector_type(2)));

// Prep: zero the loss accumulator and build e2[512] = ||emb_row||^2 in ws.
// Same ascending-k fmaf order as previous rounds (distance bit-identical).
__global__ __launch_bounds__(256) void vq_prep(const float* __restrict__ emb,
                                               float* __restrict__ out,
                                               float* __restrict__ e2) {
    const int r = blockIdx.x * 256 + threadIdx.x;   // row 0..511
    if (r == 0) out[0] = 0.0f;
    const float4* rp = (const float4*)(emb + r * DIM);
    float s = 0.f;
#pragma unroll
    for (int j = 0; j < 16; ++j) {
        float4 f = rp[j];
        s = fmaf(f.x, f.x, s);
        s = fmaf(f.y, f.y, s);
        s = fmaf(f.z, f.z, s);
        s = fmaf(f.w, f.w, s);
    }
    e2[r] = s;
}

// 256 threads = 4 waves, 64 points/block, grid 2048 (8 blocks/CU).
// 1 point per thread (z in 32 v2f; round-5 lesson: 2 pts/thread spills).
// Wave q scans codebook rows [q*128, q*128+128) -> 8192 total waves
// (round-6 lesson: 2-way split caps at 4096 waves = 4/SIMD, latency-bound).
// q is readfirstlane'd so emb addressing scalarizes to s_load (round-4
// lesson: "s" asm constraints instead caused readfirstlane chains).
__global__ __launch_bounds__(256) void vq_main(
    const float* __restrict__ z,    // [32, 64, 64, 64] NCHW
    const float* __restrict__ emb,  // [512, 64]
    const float* __restrict__ e2g,  // [512] from vq_prep
    float* __restrict__ out)        // [0] = loss, [1..] = z_q_st NCHW
{
    const int t = threadIdx.x;
    const int q = __builtin_amdgcn_readfirstlane(t >> 6);  // wave id, SGPR
    const int l = t & 63;

    __shared__ float se2[N_E];
    __shared__ float sdm[4][64];
    __shared__ int   sim[4][64];
    __shared__ float sred[4];

    // e2 table: coalesced copy from ws
    se2[t]       = e2g[t];
    se2[256 + t] = e2g[256 + t];

    // ---- load this point's z row (coalesced per channel) ----
    const int p0 = blockIdx.x * 64;
    const int b  = p0 >> 12;
    const int hw = (p0 & 4095) + l;
    const float* zb = z + (size_t)b * DIM * HW + hw;

    v2f zv[32];
    float z2 = 0.f;
#pragma unroll
    for (int k = 0; k < 32; ++k) {
        float lo = zb[(size_t)(2 * k)     * HW];
        float hi = zb[(size_t)(2 * k + 1) * HW];
        zv[k][0] = lo; zv[k][1] = hi;
        z2 = fmaf(lo, lo, z2);
        z2 = fmaf(hi, hi, z2);
    }
    __syncthreads();

    // ---- scan this wave's 128 rows; emb loads wave-uniform (scalar pipe) ----
    const float* eb  = emb + q * 128 * DIM;
    const float* e2b = se2 + q * 128;
    float dmin = 3.4e38f;
    int   imin = 0;
#pragma unroll 2
    for (int e = 0; e < 128; ++e) {
        const float4* er4 = (const float4*)(eb + e * DIM);   // 16 x float4
        v2f a0 = {0.f,0.f}, a1 = {0.f,0.f}, a2 = {0.f,0.f}, a3 = {0.f,0.f};
#pragma unroll
        for (int j = 0; j < 8; ++j) {
            float4 f0 = er4[2 * j];
            float4 f1 = er4[2 * j + 1];
            a0 = __builtin_elementwise_fma(zv[4 * j],     (v2f){f0.x, f0.y}, a0);
            a1 = __builtin_elementwise_fma(zv[4 * j + 1], (v2f){f0.z, f0.w}, a1);
            a2 = __builtin_elementwise_fma(zv[4 * j + 2], (v2f){f1.x, f1.y}, a2);
            a3 = __builtin_elementwise_fma(zv[4 * j + 3], (v2f){f1.z, f1.w}, a3);
        }
        v2f s = (a0 + a1) + (a2 + a3);
        float dot = s[0] + s[1];
        float d = fmaf(-2.0f, dot, z2 + e2b[e]);
        if (d < dmin) { dmin = d; imin = e; }
    }
    imin += q * 128;   // ascending scan + strict < => first index within range

    // ---- combine 4 quarters per point (ascending q => global first-index) ----
    sdm[q][l] = dmin;
    sim[q][l] = imin;
    __syncthreads();
    float bd = sdm[0][l];
    int   bi = sim[0][l];
#pragma unroll
    for (int qq = 1; qq < 4; ++qq) {
        float d2 = sdm[qq][l];
        int   i2 = sim[qq][l];
        if (d2 < bd) { bd = d2; bi = i2; }
    }
    const int w = bi;   // same in all 4 waves for point l

    // ---- epilogue: wave q writes channels [16q, 16q+16) of its point ----
    float acc = 0.f;
    float* ob = out + 1 + (size_t)b * DIM * HW + hw;

#define EPI(Q)                                                          \
    {                                                                   \
        _Pragma("unroll")                                               \
        for (int j = 0; j < 16; ++j) {                                  \
            const int c = (Q) * 16 + j;                                 \
            float v = emb[w * DIM + c];                                 \
            ob[(size_t)c * HW] = v;                                     \
            float zc = (c & 1) ? zv[c >> 1][1] : zv[c >> 1][0];         \
            float d = v - zc;                                           \
            acc = fmaf(d, d, acc);                                      \
        }                                                               \
    }
    if (q == 0)      EPI(0)
    else if (q == 1) EPI(1)
    else if (q == 2) EPI(2)
    else             EPI(3)
#undef EPI

    // ---- loss reduction: wave shuffle -> LDS -> one atomic per block ----
#pragma unroll
    for (int o = 32; o > 0; o >>= 1) acc += __shfl_down(acc, o, 64);
    if (l == 0) sred[q] = acc;
    __syncthreads();
    if (t == 0) {
        float s = (sred[0] + sred[1]) + (sred[2] + sred[3]);
        atomicAdd(out, s * (1.25f / (float)OUT_ELEMS));
    }
}

extern "C" void kernel_launch(void* const* d_in, const int* in_sizes, int n_in,
                              void* d_out, int out_size, void* d_ws, size_t ws_size,
                              hipStream_t stream) {
    const float* z   = (const float*)d_in[0];
    const float* emb = (const float*)d_in[1];
    float* out = (float*)d_out;
    float* e2  = (float*)d_ws;

    vq_prep<<<2, 256, 0, stream>>>(emb, out, e2);
    vq_main<<<NPTS / 64, 256, 0, stream>>>(z, emb, e2, out);
}